// Round 9
// baseline (335.754 us; speedup 1.0000x reference)
//
#include <hip/hip_runtime.h>

// Problem constants
#define BATCH   4096
#define NF      39          // num_field
#define ED      16          // embedding size
#define IN_DIM  624         // NF*ED
#define DW      400
#define BN_EPS  1e-5f
#define NKSG    78          // CIN K-steps: 39 m * 64 h / 32
#define AK1     640         // padded deep K for layer 1 input (624 -> 640)
#define NKS1    20          // AK1/32
#define NKS2    13          // 400 -> 416 padded
#define WCOL    416         // padded deep-weight column count

typedef __attribute__((ext_vector_type(8))) short short8;
typedef __attribute__((ext_vector_type(4))) float f32x4;
typedef __attribute__((ext_vector_type(2))) float f32x2;
typedef unsigned short u16;

__device__ inline unsigned pack_hi2(float a, float b) {
  return __builtin_amdgcn_perm(__float_as_uint(b), __float_as_uint(a), 0x07060302u);
}
__device__ inline unsigned bf16_rne(float f) {
  unsigned u = __float_as_uint(f);
  u += 0x7fff + ((u >> 16) & 1);
  return u >> 16;
}
__device__ inline float bf2f(u16 v) { return __uint_as_float((unsigned)v << 16); }

#define CIN_E (NKSG * 128 * 32)      // 319488
#define D1_E  (NKS1 * WCOL * 32)     // 266240
#define D2_E  (NKS2 * WCOL * 32)     // 173056
#define PREP_E (CIN_E + D1_E + D2_E + 1600)
#define PREP_B ((PREP_E + 255) / 256)
#define GATH_B (BATCH / 4)

// ---------------------------------------------------------------------------
// Merged: blocks < GATH_B gather embeddings (wave per sample, no barriers);
// rest pack weights into B-fragment layout and zero BN-stat accumulators.
// ---------------------------------------------------------------------------
__global__ __launch_bounds__(256) void k_gp(const int* __restrict__ idx,
    const float* __restrict__ emb, const float* __restrict__ lw,
    const float* __restrict__ lb, const float* __restrict__ w1,
    const float* __restrict__ w2, const float* __restrict__ dw1,
    const float* __restrict__ dw2, u16* __restrict__ flatb,
    float* __restrict__ lp, u16* __restrict__ wp1, u16* __restrict__ wp2,
    u16* __restrict__ wpd1, u16* __restrict__ wpd2, float* __restrict__ gstat) {
  int t = threadIdx.x;
  if (blockIdx.x < GATH_B) {
    int lane = t & 63;
    int b = blockIdx.x * 4 + (t >> 6);
    int sj = (lane < NF) ? idx[b * NF + lane] : 0;
    float acc = 0.f;
#pragma unroll
    for (int i = 0; i < 10; i++) {
      int e = lane + i * 64;
      if (e < IN_DIM) {
        int f = e >> 4;
        int row = __shfl(sj, f);
        float v = emb[(size_t)row * ED + (e & 15)];
        flatb[(size_t)b * AK1 + e] = (u16)bf16_rne(v);
        acc = fmaf(v, lw[e], acc);
      } else {
        flatb[(size_t)b * AK1 + e] = 0;
      }
    }
#pragma unroll
    for (int k = 1; k < 64; k <<= 1) acc += __shfl_xor(acc, k);
    if (lane == 0) lp[b] = acc + lb[0];
  } else {
    int e = (blockIdx.x - GATH_B) * 256 + t;
    if (e < CIN_E) {
      int ksg = e >> 12, r = e & 4095, n = r >> 5, kk = r & 31;
      int k = ksg * 32 + kk, h = k & 63, m = k >> 6;
      float v1 = (h < NF) ? w1[(size_t)n * (NF * NF) + h * NF + m] : 0.f;
      float v2 = w2[(size_t)n * (64 * NF) + h * NF + m];
      wp1[e] = (u16)bf16_rne(v1);
      wp2[e] = (u16)bf16_rne(v2);
    } else if (e < CIN_E + D1_E) {
      int e2 = e - CIN_E;
      int ksg = e2 / (WCOL * 32), r = e2 - ksg * (WCOL * 32);
      int col = r >> 5, kk = r & 31;
      int k = ksg * 32 + kk;
      wpd1[e2] = (k < IN_DIM && col < DW) ? (u16)bf16_rne(dw1[(size_t)k * DW + col]) : 0;
    } else if (e < CIN_E + D1_E + D2_E) {
      int e2 = e - CIN_E - D1_E;
      int ksg = e2 / (WCOL * 32), r = e2 - ksg * (WCOL * 32);
      int col = r >> 5, kk = r & 31;
      int k = ksg * 32 + kk;
      wpd2[e2] = (k < DW && col < DW) ? (u16)bf16_rne(dw2[(size_t)k * DW + col]) : 0;
    } else if (e < PREP_E) {
      gstat[e - CIN_E - D1_E - D2_E] = 0.f;
    }
  }
}

// ---------------------------------------------------------------------------
// CIN body (r8 structure). cidx in [0,512): sample-block = cidx>>1,
// o-half c0 = (cidx&1)*64. Wave = 4 samples x 4 n-tiles; no LDS/barriers;
// s1 pre-unpacked f32 pairs; B prefetch distance 2 via 3-slot ring.
// ---------------------------------------------------------------------------
template <bool LAY2>
__device__ __forceinline__ void cin_body(int cidx, int t,
    const u16* __restrict__ flatb, const u16* __restrict__ nxtg,
    const u16* __restrict__ wp, const float* __restrict__ bias,
    u16* __restrict__ nxt_out, float* __restrict__ res) {
  int w = t >> 6, lane = t & 63;
  int nl = lane & 15, q = lane >> 4;
  int d = nl;
  int b0 = (cidx >> 1) * 16 + w * 4;
  int c0 = (cidx & 1) * 64;

  f32x2 nxf[4][2][4];
  if (LAY2) {
#pragma unroll
    for (int si = 0; si < 4; si++)
#pragma unroll
      for (int ks = 0; ks < 2; ks++) {
        uint4 v = *(const uint4*)(nxtg +
            (((size_t)(b0 + si) * 16 + d) * 64 + ks * 32 + q * 8));
        unsigned uu[4] = {v.x, v.y, v.z, v.w};
#pragma unroll
        for (int w4 = 0; w4 < 4; w4++)
          nxf[si][ks][w4] = (f32x2){__uint_as_float(uu[w4] << 16),
                                    __uint_as_float(uu[w4] & 0xffff0000u)};
      }
  } else {
#pragma unroll
    for (int si = 0; si < 4; si++)
#pragma unroll
      for (int ks = 0; ks < 2; ks++)
#pragma unroll
        for (int w4 = 0; w4 < 4; w4++) {
          int h0 = ks * 32 + q * 8 + 2 * w4;
          int h1 = h0 + 1;
          float f0 = (h0 < NF) ? bf2f(flatb[(size_t)(b0 + si) * AK1 + h0 * 16 + d]) : 0.f;
          float f1 = (h1 < NF) ? bf2f(flatb[(size_t)(b0 + si) * AK1 + h1 * 16 + d]) : 0.f;
          nxf[si][ks][w4] = (f32x2){f0, f1};
        }
  }

  f32x4 acc[4][4];
#pragma unroll
  for (int si = 0; si < 4; si++)
#pragma unroll
    for (int nt = 0; nt < 4; nt++) acc[si][nt] = (f32x4){0.f, 0.f, 0.f, 0.f};

  const u16* wbase = wp + (size_t)(c0 + nl) * 32 + q * 8;
  short8 bfr[3][4];
#pragma unroll
  for (int nt = 0; nt < 4; nt++) {
    bfr[0][nt] = *(const short8*)(wbase + nt * 512);
    bfr[1][nt] = *(const short8*)(wbase + 4096 + nt * 512);
  }

  float xv[4], xvn[4];
#pragma unroll
  for (int si = 0; si < 4; si++)
    xv[si] = bf2f(flatb[(size_t)(b0 + si) * AK1 + d]);

  for (int mg = 0; mg < 13; mg++) {
#pragma unroll
    for (int j = 0; j < 6; j++) {
      int ksg = mg * 6 + j;
      int ks = j & 1;
      if (j < 4 || mg < 12) {
        const u16* wb = wbase + (size_t)(ksg + 2) * 4096;
#pragma unroll
        for (int nt = 0; nt < 4; nt++)
          bfr[(j + 2) % 3][nt] = *(const short8*)(wb + nt * 512);
      }
      if (ks == 0) {
        int m = ksg >> 1;
#pragma unroll
        for (int si = 0; si < 4; si++)
          xvn[si] = bf2f(flatb[(size_t)(b0 + si) * AK1 + (m + 1) * 16 + d]);
      }
      short8 afr[4];
#pragma unroll
      for (int si = 0; si < 4; si++) {
        union { unsigned u[4]; short8 s; } a;
        f32x2 xv2 = (f32x2){xv[si], xv[si]};
#pragma unroll
        for (int w4 = 0; w4 < 4; w4++) {
          f32x2 p = nxf[si][ks][w4] * xv2;
          a.u[w4] = pack_hi2(p[0], p[1]);
        }
        afr[si] = a.s;
      }
#pragma unroll
      for (int nt = 0; nt < 4; nt++)
#pragma unroll
        for (int si = 0; si < 4; si++)
          acc[si][nt] = __builtin_amdgcn_mfma_f32_16x16x32_bf16(
              afr[si], bfr[j % 3][nt], acc[si][nt], 0, 0, 0);
      if (ks == 1) {
#pragma unroll
        for (int si = 0; si < 4; si++) xv[si] = xvn[si];
      }
    }
  }

#pragma unroll
  for (int si = 0; si < 4; si++) {
    int b = b0 + si;
#pragma unroll
    for (int nt = 0; nt < 4; nt++) {
      int o = c0 + nt * 16 + nl;
      float bi = bias[o];
      if (!LAY2 && c0 == 0) {
#pragma unroll
        for (int r = 0; r < 4; r++) {
          float v = fmaxf(acc[si][nt][r] + bi, 0.f);
          nxt_out[((size_t)b * 16 + q * 4 + r) * 64 + o] = (u16)bf16_rne(v);
        }
      } else {
        float s = 0.f;
#pragma unroll
        for (int r = 0; r < 4; r++) s += fmaxf(acc[si][nt][r] + bi, 0.f);
        s += __shfl_xor(s, 16);
        s += __shfl_xor(s, 32);
        if (q == 0) {
          int ri = LAY2 ? (64 + o) : (o - 64);
          res[(size_t)b * 192 + ri] = s;
        }
      }
    }
  }
}

// ---------------------------------------------------------------------------
// Deep-tower GEMM body (r8 structure). gx in [0,64), gy in [0,13).
// ---------------------------------------------------------------------------
template <bool BN_A, int NKS, int KREAL, int AK>
__device__ __forceinline__ void gemm_body(int gx, int gy, int t,
    float* lsS, float* lsH, float* lred,
    const u16* __restrict__ Abf, const float* __restrict__ Af32,
    const u16* __restrict__ wp, const float* __restrict__ bias,
    const float* __restrict__ gsIn, const float* __restrict__ gs2In,
    const float* __restrict__ bng, const float* __restrict__ bnb,
    float* __restrict__ C, float* __restrict__ gs, float* __restrict__ gs2) {
  if (BN_A) {
    for (int c = t; c < NKS * 32; c += 256) {
      float sc = 0.f, sh = 0.f;
      if (c < DW) {
        float m = gsIn[c] * (1.f / BATCH);
        float var = gs2In[c] * (1.f / BATCH) - m * m;
        sc = bng[c] * rsqrtf(var + BN_EPS);
        sh = bnb[c] - m * sc;
      }
      lsS[c] = sc; lsH[c] = sh;
    }
  }
  if (t < 64) lred[t] = 0.f;
  __syncthreads();

  int w = t >> 6, lane = t & 63;
  int nl = lane & 15, q = lane >> 4;
  int row = gx * 64 + w * 16 + nl;
  int c0 = gy * 32;
  f32x4 acc[2];
  acc[0] = (f32x4){0.f, 0.f, 0.f, 0.f};
  acc[1] = (f32x4){0.f, 0.f, 0.f, 0.f};

  short8 araw[2]; f32x4 fraw0[2], fraw1[2]; short8 braw[2][2];
  auto loadA_raw = [&](int ksg, int buf) {
    int kb = ksg * 32 + q * 8;
    if (!BN_A) {
      araw[buf] = *(const short8*)(Abf + (size_t)row * AK + kb);
    } else {
      if (kb + 8 <= KREAL) {
        fraw0[buf] = *(const f32x4*)(Af32 + (size_t)row * KREAL + kb);
        fraw1[buf] = *(const f32x4*)(Af32 + (size_t)row * KREAL + kb + 4);
      } else {
        fraw0[buf] = (f32x4){0.f,0.f,0.f,0.f};
        fraw1[buf] = (f32x4){0.f,0.f,0.f,0.f};
      }
    }
    const u16* wb = wp + (size_t)ksg * (WCOL * 32) + (size_t)(c0 + nl) * 32 + q * 8;
    braw[buf][0] = *(const short8*)wb;
    braw[buf][1] = *(const short8*)(wb + 16 * 32);
  };
  auto cookA = [&](int ksg, int buf) -> short8 {
    if (!BN_A) return araw[buf];
    int kb = ksg * 32 + q * 8;
    f32x4 s0 = *(const f32x4*)&lsS[kb], h0 = *(const f32x4*)&lsH[kb];
    f32x4 s1 = *(const f32x4*)&lsS[kb + 4], h1 = *(const f32x4*)&lsH[kb + 4];
    union { unsigned u[4]; short8 s; } a;
    float v0 = fmaxf(fmaf(fraw0[buf][0], s0[0], h0[0]), 0.f);
    float v1 = fmaxf(fmaf(fraw0[buf][1], s0[1], h0[1]), 0.f);
    float v2 = fmaxf(fmaf(fraw0[buf][2], s0[2], h0[2]), 0.f);
    float v3 = fmaxf(fmaf(fraw0[buf][3], s0[3], h0[3]), 0.f);
    float v4 = fmaxf(fmaf(fraw1[buf][0], s1[0], h1[0]), 0.f);
    float v5 = fmaxf(fmaf(fraw1[buf][1], s1[1], h1[1]), 0.f);
    float v6 = fmaxf(fmaf(fraw1[buf][2], s1[2], h1[2]), 0.f);
    float v7 = fmaxf(fmaf(fraw1[buf][3], s1[3], h1[3]), 0.f);
    a.u[0] = bf16_rne(v0) | (bf16_rne(v1) << 16);
    a.u[1] = bf16_rne(v2) | (bf16_rne(v3) << 16);
    a.u[2] = bf16_rne(v4) | (bf16_rne(v5) << 16);
    a.u[3] = bf16_rne(v6) | (bf16_rne(v7) << 16);
    return a.s;
  };

  loadA_raw(0, 0);
#pragma unroll 4
  for (int ksg = 0; ksg < NKS; ksg++) {
    int cur = ksg & 1;
    if (ksg + 1 < NKS) loadA_raw(ksg + 1, cur ^ 1);
    short8 afr = cookA(ksg, cur);
    acc[0] = __builtin_amdgcn_mfma_f32_16x16x32_bf16(afr, braw[cur][0], acc[0], 0, 0, 0);
    acc[1] = __builtin_amdgcn_mfma_f32_16x16x32_bf16(afr, braw[cur][1], acc[1], 0, 0, 0);
  }

  int rbase = gx * 64 + w * 16 + q * 4;
#pragma unroll
  for (int nt = 0; nt < 2; nt++) {
    int col = c0 + nt * 16 + nl;
    if (col < DW) {
      float bi = bias[col];
      float s = 0.f, s2 = 0.f;
#pragma unroll
      for (int r = 0; r < 4; r++) {
        float v = acc[nt][r] + bi;
        C[(size_t)(rbase + r) * DW + col] = v;
        s += v; s2 = fmaf(v, v, s2);
      }
      s += __shfl_xor(s, 16); s2 += __shfl_xor(s2, 16);
      s += __shfl_xor(s, 32); s2 += __shfl_xor(s2, 32);
      if (q == 0) {
        atomicAdd(&lred[nt * 16 + nl], s);
        atomicAdd(&lred[32 + nt * 16 + nl], s2);
      }
    }
  }
  __syncthreads();
  if (t < 32) {
    int col = c0 + t;
    if (col < DW) atomicAdd(&gs[col], lred[t]);
  } else if (t < 64) {
    int col = c0 + t - 32;
    if (col < DW) atomicAdd(&gs2[col], lred[t]);
  }
}

template <bool PH2>
__device__ __forceinline__ void gemm_go(int gx, int gy, int t,
    float* lsS, float* lsH, float* lred,
    const u16* Abf, const float* Af32, const u16* wpd, const float* dbias,
    const float* gsIn, const float* gs2In, const float* bng, const float* bnb,
    float* C, float* gs, float* gs2) {
  if (PH2)
    gemm_body<true, NKS2, DW, 0>(gx, gy, t, lsS, lsH, lred, Abf, Af32, wpd,
        dbias, gsIn, gs2In, bng, bnb, C, gs, gs2);
  else
    gemm_body<false, NKS1, IN_DIM, AK1>(gx, gy, t, lsS, lsH, lred, Abf, Af32,
        wpd, dbias, gsIn, gs2In, bng, bnb, C, gs, gs2);
}

// ---------------------------------------------------------------------------
// Fused concurrent launch: 1344 blocks. bid<1024: even -> cin block
// (cidx=bid>>1, 512 total), odd -> gemm block (g=bid>>1); bid>=1024 ->
// gemm block (g=bid-512, total 832). Interleave puts ~1 cin + 1 gemm
// per CU so gemm waves issue into cin's stall slots.
// ---------------------------------------------------------------------------
template <bool PH2>
__global__ __launch_bounds__(256, 2) void k_fused(
    const u16* __restrict__ flatb, const u16* __restrict__ nxtg,
    const u16* __restrict__ wpc, const float* __restrict__ cbias,
    u16* __restrict__ nxt_out, float* __restrict__ res,
    const u16* __restrict__ Abf, const float* __restrict__ Af32,
    const u16* __restrict__ wpd, const float* __restrict__ dbias,
    const float* __restrict__ gsIn, const float* __restrict__ gs2In,
    const float* __restrict__ bng, const float* __restrict__ bnb,
    float* __restrict__ C, float* __restrict__ gs, float* __restrict__ gs2) {
  __shared__ float lsS[640], lsH[640], lred[64];
  int bid = blockIdx.x;
  int t = threadIdx.x;
  if (bid < 1024) {
    if (!(bid & 1)) {
      cin_body<PH2>(bid >> 1, t, flatb, nxtg, wpc, cbias, nxt_out, res);
      return;
    }
    gemm_go<PH2>((bid >> 1) & 63, (bid >> 1) >> 6, t, lsS, lsH, lred,
                 Abf, Af32, wpd, dbias, gsIn, gs2In, bng, bnb, C, gs, gs2);
  } else {
    int g = bid - 512;
    gemm_go<PH2>(g & 63, g >> 6, t, lsS, lsH, lred,
                 Abf, Af32, wpd, dbias, gsIn, gs2In, bng, bnb, C, gs, gs2);
  }
}

// Standalone wrappers (fallback path when ws too small for de-aliased y2)
template <bool LAY2>
__global__ __launch_bounds__(256, 2) void k_cin_mfma(
    const u16* __restrict__ flatb, const u16* __restrict__ nxtg,
    const u16* __restrict__ wp, const float* __restrict__ bias,
    u16* __restrict__ nxt_out, float* __restrict__ res) {
  cin_body<LAY2>(blockIdx.x * 2 + blockIdx.y, threadIdx.x, flatb, nxtg, wp,
                 bias, nxt_out, res);
}

template <bool PH2>
__global__ __launch_bounds__(256) void k_gemm_mfma(
    const u16* __restrict__ Abf, const float* __restrict__ Af32,
    const u16* __restrict__ wp, const float* __restrict__ bias,
    const float* __restrict__ gsIn, const float* __restrict__ gs2In,
    const float* __restrict__ bng, const float* __restrict__ bnb,
    float* __restrict__ C, float* __restrict__ gs, float* __restrict__ gs2) {
  __shared__ float lsS[640], lsH[640], lred[64];
  gemm_go<PH2>(blockIdx.x, blockIdx.y, threadIdx.x, lsS, lsH, lred,
               Abf, Af32, wp, bias, gsIn, gs2In, bng, bnb, C, gs, gs2);
}

// ---------------------------------------------------------------------------
// Final concat + dot, BN2 finalize folded in-block.
// ---------------------------------------------------------------------------
__global__ __launch_bounds__(256) void k_final(const float* __restrict__ lp,
    const float* __restrict__ res, const float* __restrict__ y2,
    const float* __restrict__ gB, const float* __restrict__ gB2,
    const float* __restrict__ g2, const float* __restrict__ bb2,
    const float* __restrict__ ow, const float* __restrict__ ob,
    float* __restrict__ out) {
  __shared__ float lsS[DW], lsH[DW];
  int t = threadIdx.x;
  for (int c = t; c < DW; c += 256) {
    float m = gB[c] * (1.f / BATCH);
    float var = gB2[c] * (1.f / BATCH) - m * m;
    float sc = g2[c] * rsqrtf(var + BN_EPS);
    lsS[c] = sc;
    lsH[c] = bb2[c] - m * sc;
  }
  __syncthreads();
  int lane = t & 63, w = t >> 6;
  int b = blockIdx.x * 4 + w;
  float acc = 0.f;
  for (int j = lane; j < 593; j += 64) {
    float v;
    if (j == 0)       v = lp[b];
    else if (j < 193) v = res[(size_t)b * 192 + (j - 1)];
    else {
      int c = j - 193;
      v = fmaxf(fmaf(y2[(size_t)b * DW + c], lsS[c], lsH[c]), 0.f);
    }
    acc = fmaf(v, ow[j], acc);
  }
#pragma unroll
  for (int k = 1; k < 64; k <<= 1) acc += __shfl_xor(acc, k);
  if (lane == 0) out[b] = acc + ob[0];
}

// ---------------------------------------------------------------------------
extern "C" void kernel_launch(void* const* d_in, const int* in_sizes, int n_in,
                              void* d_out, int out_size, void* d_ws, size_t ws_size,
                              hipStream_t stream) {
  const int*   feat_index = (const int*)d_in[0];
  const float* emb = (const float*)d_in[2];
  const float* lw  = (const float*)d_in[3];
  const float* lb  = (const float*)d_in[4];
  const float* w1  = (const float*)d_in[5];
  const float* b1  = (const float*)d_in[6];
  const float* w2  = (const float*)d_in[7];
  const float* b2  = (const float*)d_in[8];
  const float* dw1 = (const float*)d_in[9];
  const float* db1 = (const float*)d_in[10];
  const float* g1  = (const float*)d_in[11];
  const float* bb1 = (const float*)d_in[12];
  const float* dw2 = (const float*)d_in[13];
  const float* db2 = (const float*)d_in[14];
  const float* g2  = (const float*)d_in[15];
  const float* bb2 = (const float*)d_in[16];
  const float* ow  = (const float*)d_in[17];
  const float* ob  = (const float*)d_in[18];

  float* ws   = (float*)d_ws;
  u16*  flatb = (u16*)ws;                  // 4096*640 bf16 = 1,310,720 f
  float* y1   = ws + 1310720;              // 4096*400 f32
  float* res  = ws + 2949120;              // 4096*192 f32
  float* lp   = ws + 3735552;              // 4096
  float* gA   = ws + 3741248;              // 400 sum
  float* gA2  = gA + 400;
  float* gB   = gA2 + 400;
  float* gB2  = gB + 400;                  // gstat: 1600 contiguous
  u16*  nxtg  = (u16*)(ws + 3742848);      // 4096*16*64 bf16 = 2,097,152 f
  u16*  wp1   = (u16*)(ws + 5840000);      // 319,488 bf16 = 159,744 f
  u16*  wp2   = (u16*)(ws + 5999744);      // 159,744 f
  u16*  wpd1  = (u16*)(ws + 6159488);      // 266,240 bf16 = 133,120 f
  u16*  wpd2  = (u16*)(ws + 6292608);      // 173,056 bf16 = 86,528 f -> 6,379,136 f
  float* out  = (float*)d_out;

  // De-aliased y2 needs 8,017,536 f = 32.1 MB of ws. Branch is constant per
  // session (ws_size fixed) -> graph-safe.
  bool bigws = ws_size >= (size_t)8017536 * 4;
  float* y2  = bigws ? (ws + 6379136) : (ws + 3742848);  // small-ws: alias nxtg

  k_gp<<<GATH_B + PREP_B, 256, 0, stream>>>(feat_index, emb, lw, lb, w1, w2,
      dw1, dw2, flatb, lp, wp1, wp2, wpd1, wpd2, gA);
  if (bigws) {
    // [cin1 || gemm1] -> [cin2 || gemm2] -> final
    k_fused<false><<<1344, 256, 0, stream>>>(
        flatb, nullptr, wp1, b1, nxtg, res,
        flatb, nullptr, wpd1, db1, nullptr, nullptr, nullptr, nullptr,
        y1, gA, gA2);
    k_fused<true><<<1344, 256, 0, stream>>>(
        flatb, nxtg, wp2, b2, nullptr, res,
        nullptr, y1, wpd2, db2, gA, gA2, g1, bb1,
        y2, gB, gB2);
  } else {
    // Sequential fallback (r8 plan; y2 aliases nxtg safely)
    k_cin_mfma<false><<<dim3(BATCH / 16, 2), 256, 0, stream>>>(
        flatb, nullptr, wp1, b1, nxtg, res);
    k_cin_mfma<true><<<dim3(BATCH / 16, 2), 256, 0, stream>>>(
        flatb, nxtg, wp2, b2, nullptr, res);
    k_gemm_mfma<false><<<dim3(BATCH / 64, 13), 256, 0, stream>>>(
        flatb, nullptr, wpd1, db1, nullptr, nullptr, nullptr, nullptr,
        y1, gA, gA2);
    k_gemm_mfma<true><<<dim3(BATCH / 64, 13), 256, 0, stream>>>(
        nullptr, y1, wpd2, db2, gA, gA2, g1, bb1, y2, gB, gB2);
  }
  k_final<<<BATCH / 4, 256, 0, stream>>>(lp, res, y2, gB, gB2, g2, bb2, ow, ob, out);
}

// Round 11
// 269.360 us; speedup vs baseline: 1.2465x; 1.2465x over previous
//
#include <hip/hip_runtime.h>

// Problem constants
#define BATCH   4096
#define NF      39          // num_field
#define ED      16          // embedding size
#define IN_DIM  624         // NF*ED
#define DW      400
#define BN_EPS  1e-5f
#define NK16    156         // CIN K-16 steps: 39 m * 64 h / 16
#define AK1     640         // padded deep K for layer 1 input (624 -> 640)
#define NKS1    20          // AK1/32
#define NKS2    13          // 400 -> 416 padded
#define WCOL    416         // padded deep-weight column count

typedef __attribute__((ext_vector_type(8))) short short8;
typedef __attribute__((ext_vector_type(16))) float f32x16;
typedef __attribute__((ext_vector_type(4))) float f32x4;
typedef __attribute__((ext_vector_type(2))) float f32x2;
typedef unsigned short u16;

__device__ inline unsigned pack_hi2(float a, float b) {
  return __builtin_amdgcn_perm(__float_as_uint(b), __float_as_uint(a), 0x07060302u);
}
__device__ inline unsigned bf16_rne(float f) {
  unsigned u = __float_as_uint(f);
  u += 0x7fff + ((u >> 16) & 1);
  return u >> 16;
}
__device__ inline float bf2f(u16 v) { return __uint_as_float((unsigned)v << 16); }

#define CIN_E (NK16 * 128 * 16)      // 319488 (same footprint as before)
#define D1_E  (NKS1 * WCOL * 32)     // 266240
#define D2_E  (NKS2 * WCOL * 32)     // 173056
#define PREP_E (CIN_E + D1_E + D2_E + 1600)
#define PREP_B ((PREP_E + 255) / 256)
#define GATH_B (BATCH / 4)

// ---------------------------------------------------------------------------
// Merged: blocks < GATH_B gather embeddings (wave per sample, no barriers);
// rest pack weights into B-fragment layout and zero BN-stat accumulators.
// CIN pack layout (32x32x16): wp[k16][col][kk], kk<16; lane reads 8 bf16 at
// col*16 + khalf*8. k = k16*16+kk -> h = k&63, m = k>>6.
// ---------------------------------------------------------------------------
__global__ __launch_bounds__(256) void k_gp(const int* __restrict__ idx,
    const float* __restrict__ emb, const float* __restrict__ lw,
    const float* __restrict__ lb, const float* __restrict__ w1,
    const float* __restrict__ w2, const float* __restrict__ dw1,
    const float* __restrict__ dw2, u16* __restrict__ flatb,
    float* __restrict__ lp, u16* __restrict__ wp1, u16* __restrict__ wp2,
    u16* __restrict__ wpd1, u16* __restrict__ wpd2, float* __restrict__ gstat) {
  int t = threadIdx.x;
  if (blockIdx.x < GATH_B) {
    int lane = t & 63;
    int b = blockIdx.x * 4 + (t >> 6);
    int sj = (lane < NF) ? idx[b * NF + lane] : 0;
    float acc = 0.f;
#pragma unroll
    for (int i = 0; i < 10; i++) {
      int e = lane + i * 64;
      if (e < IN_DIM) {
        int f = e >> 4;
        int row = __shfl(sj, f);
        float v = emb[(size_t)row * ED + (e & 15)];
        flatb[(size_t)b * AK1 + e] = (u16)bf16_rne(v);
        acc = fmaf(v, lw[e], acc);
      } else {
        flatb[(size_t)b * AK1 + e] = 0;
      }
    }
#pragma unroll
    for (int k = 1; k < 64; k <<= 1) acc += __shfl_xor(acc, k);
    if (lane == 0) lp[b] = acc + lb[0];
  } else {
    int e = (blockIdx.x - GATH_B) * 256 + t;
    if (e < CIN_E) {
      int k16 = e >> 11, r = e & 2047, col = r >> 4, kk = r & 15;
      int k = k16 * 16 + kk, h = k & 63, m = k >> 6;
      float v1 = (h < NF) ? w1[(size_t)col * (NF * NF) + h * NF + m] : 0.f;
      float v2 = w2[(size_t)col * (64 * NF) + h * NF + m];
      wp1[e] = (u16)bf16_rne(v1);
      wp2[e] = (u16)bf16_rne(v2);
    } else if (e < CIN_E + D1_E) {
      int e2 = e - CIN_E;
      int ksg = e2 / (WCOL * 32), r = e2 - ksg * (WCOL * 32);
      int col = r >> 5, kk = r & 31;
      int k = ksg * 32 + kk;
      wpd1[e2] = (k < IN_DIM && col < DW) ? (u16)bf16_rne(dw1[(size_t)k * DW + col]) : 0;
    } else if (e < CIN_E + D1_E + D2_E) {
      int e2 = e - CIN_E - D1_E;
      int ksg = e2 / (WCOL * 32), r = e2 - ksg * (WCOL * 32);
      int col = r >> 5, kk = r & 31;
      int k = ksg * 32 + kk;
      wpd2[e2] = (k < DW && col < DW) ? (u16)bf16_rne(dw2[(size_t)k * DW + col]) : 0;
    } else if (e < PREP_E) {
      gstat[e - CIN_E - D1_E - D2_E] = 0.f;
    }
  }
}

// ---------------------------------------------------------------------------
// CIN via 32x32x16 MFMA. Grid 512 blocks; block = 4 waves; wave = 2 samples
// (rows = lane&31: si=(lane>>4)&1, d=lane&15) x 128 o (4 n-tiles of 32).
// khalf = lane>>5 selects the k-subrange (A[m][k=khalf*8+j]).
// s1 held as f32 pairs sp[4][4] (32 VGPR): sp[s][w4] = {s1[h0],s1[h0+1]},
// h0 = 16*s + 8*khalf + 2*w4. A-frag = 4x(pk_mul+perm), shared by 4 mfmas.
// B prefetch distance 2 via 3-slot ring. No LDS, no barriers.
// C/D: col=lane&31, row=(r&3)+8*(r>>2)+4*khalf -> si=r>>3,
// d=(r&3)+8*((r>>2)&1)+4*khalf.
// ---------------------------------------------------------------------------
template <bool LAY2>
__global__ __launch_bounds__(256, 2) void k_cin32(
    const u16* __restrict__ flatb, const u16* __restrict__ nxtg,
    const u16* __restrict__ wp, const float* __restrict__ bias,
    u16* __restrict__ nxt_out, float* __restrict__ res) {
  int t = threadIdx.x;
  int w = t >> 6, lane = t & 63;
  int col = lane & 31, khalf = lane >> 5;
  int si = (lane >> 4) & 1, d = lane & 15;
  int b0 = blockIdx.x * 8 + w * 2;
  int b = b0 + si;                      // this lane's sample (for A/x loads)
  const u16* fb = flatb + (size_t)b * AK1;

  // s1 as f32 pairs
  f32x2 sp[4][4];
  if (LAY2) {
#pragma unroll
    for (int s = 0; s < 4; s++) {
      uint4 v = *(const uint4*)(nxtg + (((size_t)b * 16 + d) * 64 + s * 16 + khalf * 8));
      unsigned uu[4] = {v.x, v.y, v.z, v.w};
#pragma unroll
      for (int w4 = 0; w4 < 4; w4++)
        sp[s][w4] = (f32x2){__uint_as_float(uu[w4] << 16),
                            __uint_as_float(uu[w4] & 0xffff0000u)};
    }
  } else {
#pragma unroll
    for (int s = 0; s < 4; s++)
#pragma unroll
      for (int w4 = 0; w4 < 4; w4++) {
        int h0 = s * 16 + khalf * 8 + 2 * w4;
        int h1 = h0 + 1;
        float f0 = (h0 < NF) ? bf2f(fb[h0 * 16 + d]) : 0.f;
        float f1 = (h1 < NF) ? bf2f(fb[h1 * 16 + d]) : 0.f;
        sp[s][w4] = (f32x2){f0, f1};
      }
  }

  f32x16 acc[4];
#pragma unroll
  for (int nt = 0; nt < 4; nt++)
#pragma unroll
    for (int r = 0; r < 16; r++) acc[nt][r] = 0.f;

  // B base: wp[k16][cols 128][16]; lane addr = col*16 + khalf*8 (+nt*512)
  const u16* wbase = wp + (size_t)col * 16 + khalf * 8;
  short8 bfr[3][4];
#pragma unroll
  for (int nt = 0; nt < 4; nt++) {
    bfr[0][nt] = *(const short8*)(wbase + nt * 512);             // k16 = 0
    bfr[1][nt] = *(const short8*)(wbase + 2048 + nt * 512);      // k16 = 1
  }

  float xv = bf2f(fb[d]);               // m = 0
  float xvn;

  for (int mg = 0; mg < 13; mg++) {     // 13 groups x 12 k16-steps (3 mfields)
#pragma unroll
    for (int j = 0; j < 12; j++) {
      int k16 = mg * 12 + j;
      if (j == 0 || j == 4 || j == 8) {
        int mn = mg * 3 + (j >> 2) + 1; // next mfield (m=39 -> zero pad, safe)
        xvn = bf2f(fb[mn * 16 + d]);
      }
      if (j < 10 || mg < 12) {          // prefetch k16+2
        const u16* wb = wbase + (size_t)(k16 + 2) * 2048;
#pragma unroll
        for (int nt = 0; nt < 4; nt++)
          bfr[(j + 2) % 3][nt] = *(const short8*)(wb + nt * 512);
      }
      int s = j & 3;
      union { unsigned u[4]; short8 v; } a;
      f32x2 xv2 = (f32x2){xv, xv};
#pragma unroll
      for (int w4 = 0; w4 < 4; w4++) {
        f32x2 p = sp[s][w4] * xv2;      // v_pk_mul_f32
        a.u[w4] = pack_hi2(p[0], p[1]); // v_perm_b32
      }
#pragma unroll
      for (int nt = 0; nt < 4; nt++)
        acc[nt] = __builtin_amdgcn_mfma_f32_32x32x16_bf16(
            a.v, bfr[j % 3][nt], acc[nt], 0, 0, 0);
      if (s == 3) xv = xvn;
    }
  }

  // Epilogue
#pragma unroll
  for (int nt = 0; nt < 4; nt++) {
    int o = nt * 32 + col;
    float bi = bias[o];
    if (!LAY2 && nt < 2) {
      // o < 64: store relu to nxt[b][d][o] (bf16)
#pragma unroll
      for (int r = 0; r < 16; r++) {
        int si2 = r >> 3;
        int dd = (r & 3) + 8 * ((r >> 2) & 1) + 4 * khalf;
        float v = fmaxf(acc[nt][r] + bi, 0.f);
        nxt_out[((size_t)(b0 + si2) * 16 + dd) * 64 + o] = (u16)bf16_rne(v);
      }
    } else {
      float p0 = 0.f, p1 = 0.f;
#pragma unroll
      for (int r = 0; r < 8; r++)  p0 += fmaxf(acc[nt][r] + bi, 0.f);
#pragma unroll
      for (int r = 8; r < 16; r++) p1 += fmaxf(acc[nt][r] + bi, 0.f);
      p0 += __shfl_xor(p0, 32);          // add complementary d-half
      p1 += __shfl_xor(p1, 32);
      if (khalf == 0) {
        int ri = LAY2 ? (64 + o) : (o - 64);
        res[(size_t)b0 * 192 + ri] = p0;
        res[(size_t)(b0 + 1) * 192 + ri] = p1;
      }
    }
  }
}

// ---------------------------------------------------------------------------
// Deep-tower GEMM via MFMA (r8, unchanged). Grid (M/64, 13), wave = 16 rows
// x 32 cols. BN_A folds previous layer's BN finalize; fused BN stats.
// ---------------------------------------------------------------------------
template <bool BN_A, int NKS, int KREAL, int AK>
__global__ __launch_bounds__(256) void k_gemm_mfma(
    const u16* __restrict__ Abf, const float* __restrict__ Af32,
    const u16* __restrict__ wp, const float* __restrict__ bias,
    const float* __restrict__ gsIn, const float* __restrict__ gs2In,
    const float* __restrict__ bng, const float* __restrict__ bnb,
    float* __restrict__ C, float* __restrict__ gs, float* __restrict__ gs2) {
  __shared__ float lsS[NKS * 32], lsH[NKS * 32];
  __shared__ float lred[64];
  int t = threadIdx.x;
  if (BN_A) {
    for (int c = t; c < NKS * 32; c += 256) {
      float sc = 0.f, sh = 0.f;
      if (c < DW) {
        float m = gsIn[c] * (1.f / BATCH);
        float var = gs2In[c] * (1.f / BATCH) - m * m;
        sc = bng[c] * rsqrtf(var + BN_EPS);
        sh = bnb[c] - m * sc;
      }
      lsS[c] = sc; lsH[c] = sh;
    }
  }
  if (t < 64) lred[t] = 0.f;
  __syncthreads();

  int w = t >> 6, lane = t & 63;
  int nl = lane & 15, q = lane >> 4;
  int row = blockIdx.x * 64 + w * 16 + nl;
  int c0 = blockIdx.y * 32;
  f32x4 acc[2];
  acc[0] = (f32x4){0.f, 0.f, 0.f, 0.f};
  acc[1] = (f32x4){0.f, 0.f, 0.f, 0.f};

  short8 araw[2]; f32x4 fraw0[2], fraw1[2]; short8 braw[2][2];
  auto loadA_raw = [&](int ksg, int buf) {
    int kb = ksg * 32 + q * 8;
    if (!BN_A) {
      araw[buf] = *(const short8*)(Abf + (size_t)row * AK + kb);
    } else {
      if (kb + 8 <= KREAL) {
        fraw0[buf] = *(const f32x4*)(Af32 + (size_t)row * KREAL + kb);
        fraw1[buf] = *(const f32x4*)(Af32 + (size_t)row * KREAL + kb + 4);
      } else {
        fraw0[buf] = (f32x4){0.f,0.f,0.f,0.f};
        fraw1[buf] = (f32x4){0.f,0.f,0.f,0.f};
      }
    }
    const u16* wb = wp + (size_t)ksg * (WCOL * 32) + (size_t)(c0 + nl) * 32 + q * 8;
    braw[buf][0] = *(const short8*)wb;
    braw[buf][1] = *(const short8*)(wb + 16 * 32);
  };
  auto cookA = [&](int ksg, int buf) -> short8 {
    if (!BN_A) return araw[buf];
    int kb = ksg * 32 + q * 8;
    f32x4 s0 = *(const f32x4*)&lsS[kb], h0 = *(const f32x4*)&lsH[kb];
    f32x4 s1 = *(const f32x4*)&lsS[kb + 4], h1 = *(const f32x4*)&lsH[kb + 4];
    union { unsigned u[4]; short8 s; } a;
    float v0 = fmaxf(fmaf(fraw0[buf][0], s0[0], h0[0]), 0.f);
    float v1 = fmaxf(fmaf(fraw0[buf][1], s0[1], h0[1]), 0.f);
    float v2 = fmaxf(fmaf(fraw0[buf][2], s0[2], h0[2]), 0.f);
    float v3 = fmaxf(fmaf(fraw0[buf][3], s0[3], h0[3]), 0.f);
    float v4 = fmaxf(fmaf(fraw1[buf][0], s1[0], h1[0]), 0.f);
    float v5 = fmaxf(fmaf(fraw1[buf][1], s1[1], h1[1]), 0.f);
    float v6 = fmaxf(fmaf(fraw1[buf][2], s1[2], h1[2]), 0.f);
    float v7 = fmaxf(fmaf(fraw1[buf][3], s1[3], h1[3]), 0.f);
    a.u[0] = bf16_rne(v0) | (bf16_rne(v1) << 16);
    a.u[1] = bf16_rne(v2) | (bf16_rne(v3) << 16);
    a.u[2] = bf16_rne(v4) | (bf16_rne(v5) << 16);
    a.u[3] = bf16_rne(v6) | (bf16_rne(v7) << 16);
    return a.s;
  };

  loadA_raw(0, 0);
#pragma unroll 4
  for (int ksg = 0; ksg < NKS; ksg++) {
    int cur = ksg & 1;
    if (ksg + 1 < NKS) loadA_raw(ksg + 1, cur ^ 1);
    short8 afr = cookA(ksg, cur);
    acc[0] = __builtin_amdgcn_mfma_f32_16x16x32_bf16(afr, braw[cur][0], acc[0], 0, 0, 0);
    acc[1] = __builtin_amdgcn_mfma_f32_16x16x32_bf16(afr, braw[cur][1], acc[1], 0, 0, 0);
  }

  int rbase = blockIdx.x * 64 + w * 16 + q * 4;
#pragma unroll
  for (int nt = 0; nt < 2; nt++) {
    int col = c0 + nt * 16 + nl;
    if (col < DW) {
      float bi = bias[col];
      float s = 0.f, s2 = 0.f;
#pragma unroll
      for (int r = 0; r < 4; r++) {
        float v = acc[nt][r] + bi;
        C[(size_t)(rbase + r) * DW + col] = v;
        s += v; s2 = fmaf(v, v, s2);
      }
      s += __shfl_xor(s, 16); s2 += __shfl_xor(s2, 16);
      s += __shfl_xor(s, 32); s2 += __shfl_xor(s2, 32);
      if (q == 0) {
        atomicAdd(&lred[nt * 16 + nl], s);
        atomicAdd(&lred[32 + nt * 16 + nl], s2);
      }
    }
  }
  __syncthreads();
  if (t < 32) {
    int col = c0 + t;
    if (col < DW) atomicAdd(&gs[col], lred[t]);
  } else if (t < 64) {
    int col = c0 + t - 32;
    if (col < DW) atomicAdd(&gs2[col], lred[t]);
  }
}

// ---------------------------------------------------------------------------
// Final concat + dot, BN2 finalize folded in-block.
// ---------------------------------------------------------------------------
__global__ __launch_bounds__(256) void k_final(const float* __restrict__ lp,
    const float* __restrict__ res, const float* __restrict__ y2,
    const float* __restrict__ gB, const float* __restrict__ gB2,
    const float* __restrict__ g2, const float* __restrict__ bb2,
    const float* __restrict__ ow, const float* __restrict__ ob,
    float* __restrict__ out) {
  __shared__ float lsS[DW], lsH[DW];
  int t = threadIdx.x;
  for (int c = t; c < DW; c += 256) {
    float m = gB[c] * (1.f / BATCH);
    float var = gB2[c] * (1.f / BATCH) - m * m;
    float sc = g2[c] * rsqrtf(var + BN_EPS);
    lsS[c] = sc;
    lsH[c] = bb2[c] - m * sc;
  }
  __syncthreads();
  int lane = t & 63, w = t >> 6;
  int b = blockIdx.x * 4 + w;
  float acc = 0.f;
  for (int j = lane; j < 593; j += 64) {
    float v;
    if (j == 0)       v = lp[b];
    else if (j < 193) v = res[(size_t)b * 192 + (j - 1)];
    else {
      int c = j - 193;
      v = fmaxf(fmaf(y2[(size_t)b * DW + c], lsS[c], lsH[c]), 0.f);
    }
    acc = fmaf(v, ow[j], acc);
  }
#pragma unroll
  for (int k = 1; k < 64; k <<= 1) acc += __shfl_xor(acc, k);
  if (lane == 0) out[b] = acc + ob[0];
}

// ---------------------------------------------------------------------------
extern "C" void kernel_launch(void* const* d_in, const int* in_sizes, int n_in,
                              void* d_out, int out_size, void* d_ws, size_t ws_size,
                              hipStream_t stream) {
  const int*   feat_index = (const int*)d_in[0];
  const float* emb = (const float*)d_in[2];
  const float* lw  = (const float*)d_in[3];
  const float* lb  = (const float*)d_in[4];
  const float* w1  = (const float*)d_in[5];
  const float* b1  = (const float*)d_in[6];
  const float* w2  = (const float*)d_in[7];
  const float* b2  = (const float*)d_in[8];
  const float* dw1 = (const float*)d_in[9];
  const float* db1 = (const float*)d_in[10];
  const float* g1  = (const float*)d_in[11];
  const float* bb1 = (const float*)d_in[12];
  const float* dw2 = (const float*)d_in[13];
  const float* db2 = (const float*)d_in[14];
  const float* g2  = (const float*)d_in[15];
  const float* bb2 = (const float*)d_in[16];
  const float* ow  = (const float*)d_in[17];
  const float* ob  = (const float*)d_in[18];

  float* ws   = (float*)d_ws;
  u16*  flatb = (u16*)ws;                  // 4096*640 bf16 = 1,310,720 f
  float* y1   = ws + 1310720;              // 4096*400 f32
  float* res  = ws + 2949120;              // 4096*192 f32
  float* lp   = ws + 3735552;              // 4096
  float* gA   = ws + 3741248;              // 400 sum
  float* gA2  = gA + 400;
  float* gB   = gA2 + 400;
  float* gB2  = gB + 400;                  // gstat: 1600 contiguous
  u16*  nxtg  = (u16*)(ws + 3742848);      // 4096*16*64 bf16 = 2,097,152 f
  float* y2   = ws + 3742848;              // alias nxtg (dead after cin2)
  u16*  wp1   = (u16*)(ws + 5840000);      // 319,488 bf16
  u16*  wp2   = (u16*)(ws + 5999744);
  u16*  wpd1  = (u16*)(ws + 6159488);      // 266,240 bf16
  u16*  wpd2  = (u16*)(ws + 6292608);      // 173,056 bf16 -> ends 6,379,136 f
  float* out  = (float*)d_out;

  k_gp<<<GATH_B + PREP_B, 256, 0, stream>>>(feat_index, emb, lw, lb, w1, w2,
      dw1, dw2, flatb, lp, wp1, wp2, wpd1, wpd2, gA);
  k_cin32<false><<<512, 256, 0, stream>>>(flatb, nullptr, wp1, b1, nxtg, res);
  k_cin32<true><<<512, 256, 0, stream>>>(flatb, nxtg, wp2, b2, nullptr, res);
  k_gemm_mfma<false, NKS1, IN_DIM, AK1><<<dim3(BATCH / 64, 13), 256, 0, stream>>>(
      flatb, nullptr, wpd1, db1, nullptr, nullptr, nullptr, nullptr, y1, gA, gA2);
  k_gemm_mfma<true, NKS2, DW, 0><<<dim3(BATCH / 64, 13), 256, 0, stream>>>(
      nullptr, y1, wpd2, db2, gA, gA2, g1, bb1, y2, gB, gB2);
  k_final<<<BATCH / 4, 256, 0, stream>>>(lp, res, y2, gB, gB2, g2, bb2, ow, ob, out);
}